// Round 1
// baseline (1599.943 us; speedup 1.0000x reference)
//
#include <hip/hip_runtime.h>

#define NB 8
#define NC 512
#define NQ 64
#define NN 9216
#define FEPS 1e-6f

// workspace layout (floats)
static const size_t OFF_Q    = 0;                                  // [B][N][64]
static const size_t OFF_K    = OFF_Q + (size_t)NB * NN * NQ;       // [B][N][64]
static const size_t OFF_KSUM = OFF_K + (size_t)NB * NN * NQ;       // [B][64]
static const size_t OFF_XSUM = OFF_KSUM + NB * NQ;                 // [B][512]
static const size_t OFF_M1   = OFF_XSUM + NB * NC;                 // [B][8][64][512]
static const size_t OFF_M2   = OFF_M1 + (size_t)NB * 8 * NQ * NC;  // [B][64][512]
static const size_t OFF_VSUM = OFF_M2 + (size_t)NB * NQ * NC;      // [B][512]

// -------- x row sums: xsum[b][c] = sum_n x[b][c][n] --------
__launch_bounds__(256)
__global__ void xsum_kernel(const float* __restrict__ x, float* __restrict__ xsum) {
    const int b = blockIdx.y, c = blockIdx.x;
    const float* row = x + ((size_t)b * NC + c) * NN;
    float s = 0.f;
    for (int i = threadIdx.x; i < NN; i += 256) s += row[i];
#pragma unroll
    for (int m = 1; m < 64; m <<= 1) s += __shfl_xor(s, m, 64);
    __shared__ float wsum[4];
    if ((threadIdx.x & 63) == 0) wsum[threadIdx.x >> 6] = s;
    __syncthreads();
    if (threadIdx.x == 0) xsum[b * NC + c] = wsum[0] + wsum[1] + wsum[2] + wsum[3];
}

// -------- Q/K projection + L2 normalize + ksum --------
// grid (144, 8), block 256. Tile: 64 positions x 64 outputs, K-loop over 512 ch.
__launch_bounds__(256)
__global__ void qk_proj_kernel(const float* __restrict__ x,
                               const float* __restrict__ wq, const float* __restrict__ bq,
                               const float* __restrict__ wk, const float* __restrict__ bk,
                               float* __restrict__ Qo, float* __restrict__ Ko,
                               float* __restrict__ ksum) {
    __shared__ __align__(16) float xsT[64 * 68];  // [p][ch], stride 68
    __shared__ __align__(16) float wqs[64 * 68];  // [o][ch]
    __shared__ __align__(16) float wks[64 * 68];  // [o][ch]
    __shared__ float snq[64];
    __shared__ float snk[64];
    const int t = threadIdx.x;
    const int tx = t & 15, ty = t >> 4;   // pos p = tx+16i, out o = ty+16j
    const int b = blockIdx.y;
    const int n0 = blockIdx.x * 64;

    float accq[4][4] = {{0.f}}, acck[4][4] = {{0.f}};

    for (int kc = 0; kc < NC; kc += 64) {
#pragma unroll
        for (int r = 0; r < 16; ++r) {
            const int idx = r * 256 + t;
            const int row = idx >> 6, col = idx & 63;
            xsT[col * 68 + row] = x[(b * NC + kc + row) * NN + n0 + col];
            wqs[row * 68 + col] = wq[row * NC + kc + col];
            wks[row * 68 + col] = wk[row * NC + kc + col];
        }
        __syncthreads();
#pragma unroll
        for (int cg = 0; cg < 16; ++cg) {
            float4 xr[4], qr[4], kr[4];
#pragma unroll
            for (int i = 0; i < 4; ++i)
                xr[i] = *(const float4*)&xsT[(tx + 16 * i) * 68 + cg * 4];
#pragma unroll
            for (int j = 0; j < 4; ++j) {
                qr[j] = *(const float4*)&wqs[(ty + 16 * j) * 68 + cg * 4];
                kr[j] = *(const float4*)&wks[(ty + 16 * j) * 68 + cg * 4];
            }
#pragma unroll
            for (int i = 0; i < 4; ++i)
#pragma unroll
                for (int j = 0; j < 4; ++j) {
                    accq[i][j] += xr[i].x * qr[j].x + xr[i].y * qr[j].y +
                                  xr[i].z * qr[j].z + xr[i].w * qr[j].w;
                    acck[i][j] += xr[i].x * kr[j].x + xr[i].y * kr[j].y +
                                  xr[i].z * kr[j].z + xr[i].w * kr[j].w;
                }
        }
        __syncthreads();
    }
    // bias (before normalization, per reference)
#pragma unroll
    for (int j = 0; j < 4; ++j) {
        const float bqv = bq[ty + 16 * j], bkv = bk[ty + 16 * j];
#pragma unroll
        for (int i = 0; i < 4; ++i) { accq[i][j] += bqv; acck[i][j] += bkv; }
    }
    // per-position sum of squares: reduce across the 16 ty groups via LDS (reuse xsT)
    float* red = xsT;
#pragma unroll
    for (int i = 0; i < 4; ++i) {
        float sq = 0.f, sk = 0.f;
#pragma unroll
        for (int j = 0; j < 4; ++j) { sq += accq[i][j] * accq[i][j]; sk += acck[i][j] * acck[i][j]; }
        red[i * 256 + t] = sq;
        red[1024 + i * 256 + t] = sk;
    }
    __syncthreads();
    if (t < 64) {
        const int px = t & 15, pi = t >> 4;
        float sq = 0.f, sk = 0.f;
#pragma unroll
        for (int yy = 0; yy < 16; ++yy) {
            sq += red[pi * 256 + yy * 16 + px];
            sk += red[1024 + pi * 256 + yy * 16 + px];
        }
        snq[t] = rsqrtf(sq);
        snk[t] = rsqrtf(sk);
    }
    __syncthreads();
#pragma unroll
    for (int i = 0; i < 4; ++i) {
        const float sq = snq[tx + 16 * i], sk = snk[tx + 16 * i];
#pragma unroll
        for (int j = 0; j < 4; ++j) { accq[i][j] *= sq; acck[i][j] *= sk; }
    }
    // ksum[b][o] += sum over this tile's 64 positions of normalized K
#pragma unroll
    for (int j = 0; j < 4; ++j) {
        float s = acck[0][j] + acck[1][j] + acck[2][j] + acck[3][j];
#pragma unroll
        for (int m = 1; m < 16; m <<= 1) s += __shfl_xor(s, m, 64);
        if ((t & 15) == 0) atomicAdd(&ksum[b * NQ + ty + 16 * j], s);
    }
    // stage normalized tiles in LDS ([p][o]) and store coalesced
#pragma unroll
    for (int i = 0; i < 4; ++i)
#pragma unroll
        for (int j = 0; j < 4; ++j) {
            wqs[(tx + 16 * i) * 68 + ty + 16 * j] = accq[i][j];
            wks[(tx + 16 * i) * 68 + ty + 16 * j] = acck[i][j];
        }
    __syncthreads();
#pragma unroll
    for (int r = 0; r < 16; ++r) {
        const int idx = r * 256 + t;
        const int p = idx >> 6, o = idx & 63;
        Qo[(b * NN + n0 + p) * NQ + o] = wqs[p * 68 + o];
        Ko[(b * NN + n0 + p) * NQ + o] = wks[p * 68 + o];
    }
}

// -------- mat1p[b][chunk][o][c] = sum_{n in chunk} K[o,n] * x[c,n] --------
// grid (8 nchunk, 8 ctile, 8 b), block 256.
__launch_bounds__(256)
__global__ void kxt_kernel(const float* __restrict__ x, const float* __restrict__ Ko,
                           float* __restrict__ mat1p) {
    __shared__ __align__(16) float kst[64 * 68];  // [o][p]
    __shared__ __align__(16) float xs[64 * 68];   // [c][p]
    const int t = threadIdx.x;
    const int tx = t & 15, ty = t >> 4;  // c = c0+tx+16jc, o = ty+16jo
    const int nch = blockIdx.x, ct = blockIdx.y, b = blockIdx.z;
    const int c0 = ct * 64;
    const int o64 = t & 63, pg0 = t >> 6;
    float acc[4][4] = {{0.f}};
    const int pbeg = nch * 1152;
    for (int p0 = pbeg; p0 < pbeg + 1152; p0 += 64) {
        // transpose-load K tile: coalesced along o, float4 write along p
#pragma unroll
        for (int r = 0; r < 4; ++r) {
            const int pg = pg0 + 4 * r;
            float4 v;
            v.x = Ko[(b * NN + p0 + pg * 4 + 0) * NQ + o64];
            v.y = Ko[(b * NN + p0 + pg * 4 + 1) * NQ + o64];
            v.z = Ko[(b * NN + p0 + pg * 4 + 2) * NQ + o64];
            v.w = Ko[(b * NN + p0 + pg * 4 + 3) * NQ + o64];
            *(float4*)&kst[o64 * 68 + pg * 4] = v;
        }
#pragma unroll
        for (int r = 0; r < 16; ++r) {
            const int idx = r * 256 + t;
            const int row = idx >> 6, col = idx & 63;
            xs[row * 68 + col] = x[(b * NC + c0 + row) * NN + p0 + col];
        }
        __syncthreads();
#pragma unroll
        for (int p4 = 0; p4 < 64; p4 += 4) {
            float4 kr[4], xr[4];
#pragma unroll
            for (int jo = 0; jo < 4; ++jo) kr[jo] = *(const float4*)&kst[(ty + 16 * jo) * 68 + p4];
#pragma unroll
            for (int jc = 0; jc < 4; ++jc) xr[jc] = *(const float4*)&xs[(tx + 16 * jc) * 68 + p4];
#pragma unroll
            for (int jo = 0; jo < 4; ++jo)
#pragma unroll
                for (int jc = 0; jc < 4; ++jc)
                    acc[jo][jc] += kr[jo].x * xr[jc].x + kr[jo].y * xr[jc].y +
                                   kr[jo].z * xr[jc].z + kr[jo].w * xr[jc].w;
        }
        __syncthreads();
    }
#pragma unroll
    for (int jo = 0; jo < 4; ++jo)
#pragma unroll
        for (int jc = 0; jc < 4; ++jc)
            mat1p[((b * 8 + nch) * NQ + ty + 16 * jo) * NC + c0 + tx + 16 * jc] = acc[jo][jc];
}

// -------- mat2[b][o][co] = sum_c mat1[o][c]*wv[co][c] + ksum0[o]*bv[co]; vsum --------
// grid (8 cotile, 8 b), block 256.
__launch_bounds__(256)
__global__ void mat2_kernel(const float* __restrict__ wv, const float* __restrict__ bv,
                            const float* __restrict__ mat1p, const float* __restrict__ ksum,
                            const float* __restrict__ xsum,
                            float* __restrict__ mat2, float* __restrict__ vsum) {
    __shared__ __align__(16) float m1s[64 * 68];  // [o][c]
    __shared__ __align__(16) float wvs[64 * 68];  // [co][c]
    const int t = threadIdx.x;
    const int tx = t & 15, ty = t >> 4;  // co = co0+tx+16jc, o = ty+16jo
    const int ct = blockIdx.x, b = blockIdx.y;
    const int co0 = ct * 64;
    if (t < 64) {
        const int co = co0 + t;
        float s = 0.f;
        for (int c = 0; c < NC; ++c) s += wv[co * NC + c] * xsum[b * NC + c];
        vsum[b * NC + co] = s + (float)NN * bv[co];
    }
    float acc[4][4] = {{0.f}};
    for (int cc = 0; cc < NC; cc += 64) {
#pragma unroll
        for (int r = 0; r < 16; ++r) {
            const int idx = r * 256 + t;
            const int row = idx >> 6, col = idx & 63;
            float s = 0.f;
#pragma unroll
            for (int k = 0; k < 8; ++k) s += mat1p[((b * 8 + k) * NQ + row) * NC + cc + col];
            m1s[row * 68 + col] = s;
            wvs[row * 68 + col] = wv[(co0 + row) * NC + cc + col];
        }
        __syncthreads();
#pragma unroll
        for (int c4 = 0; c4 < 64; c4 += 4) {
            float4 mr[4], wr[4];
#pragma unroll
            for (int jo = 0; jo < 4; ++jo) mr[jo] = *(const float4*)&m1s[(ty + 16 * jo) * 68 + c4];
#pragma unroll
            for (int jc = 0; jc < 4; ++jc) wr[jc] = *(const float4*)&wvs[(tx + 16 * jc) * 68 + c4];
#pragma unroll
            for (int jo = 0; jo < 4; ++jo)
#pragma unroll
                for (int jc = 0; jc < 4; ++jc)
                    acc[jo][jc] += mr[jo].x * wr[jc].x + mr[jo].y * wr[jc].y +
                                   mr[jo].z * wr[jc].z + mr[jo].w * wr[jc].w;
        }
        __syncthreads();
    }
#pragma unroll
    for (int jo = 0; jo < 4; ++jo) {
        const float ks = ksum[b * NQ + ty + 16 * jo];
#pragma unroll
        for (int jc = 0; jc < 4; ++jc) {
            const int co = co0 + tx + 16 * jc;
            mat2[(b * NQ + ty + 16 * jo) * NC + co] = acc[jo][jc] + ks * bv[co];
        }
    }
}

// -------- out = x + gamma * (vsum[c] + Q^T mat2) * tailor --------
// grid (144, 8), block 256. Thread: tx = position in tile, ty*16.. = 16 channels/chunk.
__launch_bounds__(256)
__global__ void final_kernel(const float* __restrict__ x, const float* __restrict__ Qo,
                             const float* __restrict__ ksum, const float* __restrict__ mat2,
                             const float* __restrict__ vsum, const float* __restrict__ gamma,
                             float* __restrict__ out) {
    __shared__ float qs[64 * 65];                  // [p][o]
    __shared__ __align__(16) float m2s[64 * 68];   // [o][c]
    __shared__ float vs[64];
    __shared__ float ksl[64];
    __shared__ float tl[64];
    const int t = threadIdx.x;
    const int tx = t & 63, ty = t >> 6;
    const int b = blockIdx.y;
    const int n0 = blockIdx.x * 64;
#pragma unroll
    for (int r = 0; r < 16; ++r) {
        const int idx = r * 256 + t;
        const int p = idx >> 6, o = idx & 63;
        qs[p * 65 + o] = Qo[(b * NN + n0 + p) * NQ + o];
    }
    if (t < 64) ksl[t] = ksum[b * NQ + t] + FEPS;
    __syncthreads();
    if (t < 64) {
        float s = 0.f;
#pragma unroll
        for (int o = 0; o < 64; ++o) s += qs[t * 65 + o] * ksl[o];
        tl[t] = 1.0f / ((float)NN + s);
    }
    __syncthreads();
    const float g = gamma[0];
    const float tlr = tl[tx];
    for (int cc = 0; cc < NC; cc += 64) {
#pragma unroll
        for (int r = 0; r < 16; ++r) {
            const int idx = r * 256 + t;
            const int o = idx >> 6, c = idx & 63;
            m2s[o * 68 + c] = mat2[(b * NQ + o) * NC + cc + c];
        }
        if (t < 64) vs[t] = vsum[b * NC + cc + t];
        __syncthreads();
        float acc[16];
#pragma unroll
        for (int u = 0; u < 16; ++u) acc[u] = 0.f;
        for (int o = 0; o < 64; ++o) {
            const float qv = qs[tx * 65 + o];
#pragma unroll
            for (int u = 0; u < 4; ++u) {
                const float4 mv = *(const float4*)&m2s[o * 68 + ty * 16 + u * 4];
                acc[u * 4 + 0] += qv * mv.x;
                acc[u * 4 + 1] += qv * mv.y;
                acc[u * 4 + 2] += qv * mv.z;
                acc[u * 4 + 3] += qv * mv.w;
            }
        }
#pragma unroll
        for (int u = 0; u < 4; ++u)
#pragma unroll
            for (int v = 0; v < 4; ++v) {
                const int cl = ty * 16 + u * 4 + v;
                const int gi = (b * NC + cc + cl) * NN + n0 + tx;
                out[gi] = x[gi] + g * (vs[cl] + acc[u * 4 + v]) * tlr;
            }
        __syncthreads();
    }
}

extern "C" void kernel_launch(void* const* d_in, const int* in_sizes, int n_in,
                              void* d_out, int out_size, void* d_ws, size_t ws_size,
                              hipStream_t stream) {
    (void)in_sizes; (void)n_in; (void)out_size; (void)ws_size;
    const float* x     = (const float*)d_in[0];
    const float* wq    = (const float*)d_in[1];
    const float* bq    = (const float*)d_in[2];
    const float* wk    = (const float*)d_in[3];
    const float* bk    = (const float*)d_in[4];
    const float* wv    = (const float*)d_in[5];
    const float* bv    = (const float*)d_in[6];
    const float* gamma = (const float*)d_in[7];
    float* out = (float*)d_out;
    float* ws  = (float*)d_ws;

    float* Q    = ws + OFF_Q;
    float* K    = ws + OFF_K;
    float* ksum = ws + OFF_KSUM;
    float* xsum = ws + OFF_XSUM;
    float* m1p  = ws + OFF_M1;
    float* m2   = ws + OFF_M2;
    float* vsum = ws + OFF_VSUM;

    // zero the atomically-accumulated region (ksum + xsum are contiguous)
    hipMemsetAsync(ksum, 0, (size_t)(NB * NQ + NB * NC) * sizeof(float), stream);

    xsum_kernel<<<dim3(NC, NB), 256, 0, stream>>>(x, xsum);
    qk_proj_kernel<<<dim3(NN / 64, NB), 256, 0, stream>>>(x, wq, bq, wk, bk, Q, K, ksum);
    kxt_kernel<<<dim3(8, 8, NB), 256, 0, stream>>>(x, K, m1p);
    mat2_kernel<<<dim3(8, NB), 256, 0, stream>>>(wv, bv, m1p, ksum, xsum, m2, vsum);
    final_kernel<<<dim3(NN / 64, NB), 256, 0, stream>>>(x, Q, ksum, m2, vsum, gamma, out);
}

// Round 2
// 619.920 us; speedup vs baseline: 2.5809x; 2.5809x over previous
//
#include <hip/hip_runtime.h>

#define NB 8
#define NC 512
#define NQ 64
#define NN 9216
#define FEPS 1e-6f

// workspace layout (floats)
static const size_t OFF_Q    = 0;                                  // Qt [B][64][N]
static const size_t OFF_KT   = OFF_Q + (size_t)NB * NQ * NN;       // Kt [B][64][N]
static const size_t OFF_KSUM = OFF_KT + (size_t)NB * NQ * NN;      // [B][64]
static const size_t OFF_XSUM = OFF_KSUM + (size_t)NB * NQ;         // [B][512]
static const size_t OFF_M1   = OFF_XSUM + (size_t)NB * NC;         // [B][64][512]
static const size_t OFF_M2   = OFF_M1 + (size_t)NB * NQ * NC;      // [B][64][512]
static const size_t OFF_VSUM = OFF_M2 + (size_t)NB * NQ * NC;      // [B][512]

__device__ __forceinline__ void load_lds16(const float* g, float* l) {
    __builtin_amdgcn_global_load_lds((const __attribute__((address_space(1))) void*)g,
                                     (__attribute__((address_space(3))) void*)l, 16, 0, 0);
}

// -------- Q/K projection + L2 normalize + ksum; stores TRANSPOSED Qt/Kt [b][o][n] --------
// grid (144, 8), block 256.
__launch_bounds__(256, 3)
__global__ void qk_proj_kernel(const float* __restrict__ x,
                               const float* __restrict__ wq, const float* __restrict__ bq,
                               const float* __restrict__ wk, const float* __restrict__ bk,
                               float* __restrict__ Qt, float* __restrict__ Kt,
                               float* __restrict__ ksum) {
    __shared__ __align__(16) float xsT[64 * 68];   // [p][ch] stride 68 (also reused as scratch)
    __shared__ __align__(16) float wqs[64 * 64];   // [o][ch] stride 64 (global_load_lds)
    __shared__ __align__(16) float wks[64 * 64];
    __shared__ float snq[64];
    __shared__ float snk[64];
    const int t = threadIdx.x;
    const int tx = t & 15, ty = t >> 4;     // pos p = tx+16i, out o = ty+16j
    const int wid = t >> 6, lane = t & 63;
    const int lrow = lane >> 4, lcol = (lane & 15) * 4;
    const int b = blockIdx.y;
    const int n0 = blockIdx.x * 64;

    float accq[4][4] = {{0.f}}, acck[4][4] = {{0.f}};

    for (int kc = 0; kc < NC; kc += 64) {
        // weights -> LDS via async direct-to-LDS (no VGPR round-trip)
#pragma unroll
        for (int q = 0; q < 4; ++q) {
            const int o0 = q * 16 + wid * 4;
            load_lds16(wq + (size_t)(o0 + lrow) * NC + kc + lcol, &wqs[o0 * 64]);
            load_lds16(wk + (size_t)(o0 + lrow) * NC + kc + lcol, &wks[o0 * 64]);
        }
        // x tile transpose -> xsT[p][ch], float4 global reads
#pragma unroll
        for (int r = 0; r < 4; ++r) {
            const int idx = r * 256 + t;
            const int ch = idx >> 4, a = (idx & 15) * 4;
            const float4 v = *(const float4*)&x[((size_t)b * NC + kc + ch) * NN + n0 + a];
            xsT[(a + 0) * 68 + ch] = v.x;
            xsT[(a + 1) * 68 + ch] = v.y;
            xsT[(a + 2) * 68 + ch] = v.z;
            xsT[(a + 3) * 68 + ch] = v.w;
        }
        __syncthreads();
#pragma unroll 8
        for (int cg = 0; cg < 16; ++cg) {
            float4 xr[4], qr[4], kr[4];
#pragma unroll
            for (int i = 0; i < 4; ++i)
                xr[i] = *(const float4*)&xsT[(tx + 16 * i) * 68 + cg * 4];
#pragma unroll
            for (int j = 0; j < 4; ++j) {
                qr[j] = *(const float4*)&wqs[(ty + 16 * j) * 64 + cg * 4];
                kr[j] = *(const float4*)&wks[(ty + 16 * j) * 64 + cg * 4];
            }
#pragma unroll
            for (int i = 0; i < 4; ++i)
#pragma unroll
                for (int j = 0; j < 4; ++j) {
                    accq[i][j] += xr[i].x * qr[j].x + xr[i].y * qr[j].y +
                                  xr[i].z * qr[j].z + xr[i].w * qr[j].w;
                    acck[i][j] += xr[i].x * kr[j].x + xr[i].y * kr[j].y +
                                  xr[i].z * kr[j].z + xr[i].w * kr[j].w;
                }
        }
        __syncthreads();
    }
    // bias (before normalization, per reference)
#pragma unroll
    for (int j = 0; j < 4; ++j) {
        const float bqv = bq[ty + 16 * j], bkv = bk[ty + 16 * j];
#pragma unroll
        for (int i = 0; i < 4; ++i) { accq[i][j] += bqv; acck[i][j] += bkv; }
    }
    // per-position sum of squares: reduce across the 16 ty groups via LDS (reuse xsT)
    float* red = xsT;
#pragma unroll
    for (int i = 0; i < 4; ++i) {
        float sq = 0.f, sk = 0.f;
#pragma unroll
        for (int j = 0; j < 4; ++j) { sq += accq[i][j] * accq[i][j]; sk += acck[i][j] * acck[i][j]; }
        red[i * 256 + t] = sq;
        red[1024 + i * 256 + t] = sk;
    }
    __syncthreads();
    if (t < 64) {
        const int px = t & 15, pi = t >> 4;
        float sq = 0.f, sk = 0.f;
#pragma unroll
        for (int yy = 0; yy < 16; ++yy) {
            sq += red[pi * 256 + yy * 16 + px];
            sk += red[1024 + pi * 256 + yy * 16 + px];
        }
        snq[t] = rsqrtf(sq);
        snk[t] = rsqrtf(sk);
    }
    __syncthreads();
#pragma unroll
    for (int i = 0; i < 4; ++i) {
        const float sq = snq[tx + 16 * i], sk = snk[tx + 16 * i];
#pragma unroll
        for (int j = 0; j < 4; ++j) { accq[i][j] *= sq; acck[i][j] *= sk; }
    }
    // ksum[b][o] += sum over this tile's 64 positions of normalized K
#pragma unroll
    for (int j = 0; j < 4; ++j) {
        float s = acck[0][j] + acck[1][j] + acck[2][j] + acck[3][j];
#pragma unroll
        for (int m = 1; m < 16; m <<= 1) s += __shfl_xor(s, m, 64);
        if ((t & 15) == 0) atomicAdd(&ksum[b * NQ + ty + 16 * j], s);
    }
    // stage [p][o] (stride 65, conflict-free both ways), store transposed, Q then K
    float* ep = xsT;
#pragma unroll
    for (int i = 0; i < 4; ++i)
#pragma unroll
        for (int j = 0; j < 4; ++j)
            ep[(tx + 16 * i) * 65 + ty + 16 * j] = accq[i][j];
    __syncthreads();
#pragma unroll 2
    for (int r = 0; r < 4; ++r) {
        const int idx = r * 256 + t;
        const int o = idx >> 4, p4 = (idx & 15) * 4;
        float4 v;
        v.x = ep[(p4 + 0) * 65 + o];
        v.y = ep[(p4 + 1) * 65 + o];
        v.z = ep[(p4 + 2) * 65 + o];
        v.w = ep[(p4 + 3) * 65 + o];
        *(float4*)&Qt[((size_t)b * NQ + o) * NN + n0 + p4] = v;
    }
    __syncthreads();
#pragma unroll
    for (int i = 0; i < 4; ++i)
#pragma unroll
        for (int j = 0; j < 4; ++j)
            ep[(tx + 16 * i) * 65 + ty + 16 * j] = acck[i][j];
    __syncthreads();
#pragma unroll 2
    for (int r = 0; r < 4; ++r) {
        const int idx = r * 256 + t;
        const int o = idx >> 4, p4 = (idx & 15) * 4;
        float4 v;
        v.x = ep[(p4 + 0) * 65 + o];
        v.y = ep[(p4 + 1) * 65 + o];
        v.z = ep[(p4 + 2) * 65 + o];
        v.w = ep[(p4 + 3) * 65 + o];
        *(float4*)&Kt[((size_t)b * NQ + o) * NN + n0 + p4] = v;
    }
}

// -------- mat1[b][o][c] += sum_{n in chunk} Kt[o,n]*x[c,n]; xsum[b][c] += sum_n x[c,n] --------
// grid (8 nchunk, 8 ctile, 8 b), block 256. Accumulation via device-scope atomics.
__launch_bounds__(256, 4)
__global__ void kxt_kernel(const float* __restrict__ x, const float* __restrict__ Kt,
                           float* __restrict__ mat1, float* __restrict__ xsum) {
    __shared__ __align__(16) float kst[64 * 64];  // [o][p] stride 64 (global_load_lds)
    __shared__ __align__(16) float xs[64 * 68];   // [c][p] stride 68
    const int t = threadIdx.x;
    const int tx = t & 15, ty = t >> 4;  // c = c0+tx+16jc, o = ty+16jo
    const int wid = t >> 6, lane = t & 63;
    const int lrow = lane >> 4, lcol = (lane & 15) * 4;
    const int nch = blockIdx.x, ct = blockIdx.y, b = blockIdx.z;
    const int c0 = ct * 64;
    float acc[4][4] = {{0.f}};
    float xsacc = 0.f;
    const int pbeg = nch * 1152;
    for (int p0 = pbeg; p0 < pbeg + 1152; p0 += 64) {
#pragma unroll
        for (int q = 0; q < 4; ++q) {
            const int o0 = q * 16 + wid * 4;
            load_lds16(Kt + ((size_t)b * NQ + o0 + lrow) * NN + p0 + lcol, &kst[o0 * 64]);
        }
#pragma unroll
        for (int r = 0; r < 4; ++r) {
            const int idx = r * 256 + t;
            const int c = idx >> 4, a = (idx & 15) * 4;
            *(float4*)&xs[c * 68 + a] = *(const float4*)&x[((size_t)b * NC + c0 + c) * NN + p0 + a];
        }
        __syncthreads();
        // xsum partial: thread covers c = t>>2, 16 positions at (t&3)*16
        {
            const float* bp = &xs[(t >> 2) * 68 + (t & 3) * 16];
            const float4 s0 = *(const float4*)&bp[0];
            const float4 s1 = *(const float4*)&bp[4];
            const float4 s2 = *(const float4*)&bp[8];
            const float4 s3 = *(const float4*)&bp[12];
            xsacc += (s0.x + s0.y + s0.z + s0.w) + (s1.x + s1.y + s1.z + s1.w) +
                     (s2.x + s2.y + s2.z + s2.w) + (s3.x + s3.y + s3.z + s3.w);
        }
#pragma unroll 8
        for (int p4 = 0; p4 < 16; ++p4) {
            float4 kr[4], xr[4];
#pragma unroll
            for (int jo = 0; jo < 4; ++jo) kr[jo] = *(const float4*)&kst[(ty + 16 * jo) * 64 + p4 * 4];
#pragma unroll
            for (int jc = 0; jc < 4; ++jc) xr[jc] = *(const float4*)&xs[(tx + 16 * jc) * 68 + p4 * 4];
#pragma unroll
            for (int jo = 0; jo < 4; ++jo)
#pragma unroll
                for (int jc = 0; jc < 4; ++jc)
                    acc[jo][jc] += kr[jo].x * xr[jc].x + kr[jo].y * xr[jc].y +
                                   kr[jo].z * xr[jc].z + kr[jo].w * xr[jc].w;
        }
        __syncthreads();
    }
#pragma unroll
    for (int jo = 0; jo < 4; ++jo)
#pragma unroll
        for (int jc = 0; jc < 4; ++jc)
            atomicAdd(&mat1[((size_t)b * NQ + ty + 16 * jo) * NC + c0 + tx + 16 * jc], acc[jo][jc]);
    float s = xsacc;
    s += __shfl_xor(s, 1, 64);
    s += __shfl_xor(s, 2, 64);
    if ((t & 3) == 0) atomicAdd(&xsum[b * NC + c0 + (t >> 2)], s);
}

// -------- mat2[b][o][co] = sum_c mat1[o][c]*wv[co][c] + ksum0[o]*bv[co]; vsum --------
// grid (8 cotile, 8 b), block 256.
__launch_bounds__(256)
__global__ void mat2_kernel(const float* __restrict__ wv, const float* __restrict__ bv,
                            const float* __restrict__ mat1, const float* __restrict__ ksum,
                            const float* __restrict__ xsum,
                            float* __restrict__ mat2, float* __restrict__ vsum) {
    __shared__ __align__(16) float m1s[64 * 68];  // [o][c]
    __shared__ __align__(16) float wvs[64 * 68];  // [co][c]
    const int t = threadIdx.x;
    const int tx = t & 15, ty = t >> 4;  // co = co0+tx+16jc, o = ty+16jo
    const int ct = blockIdx.x, b = blockIdx.y;
    const int co0 = ct * 64;
    if (t < 64) {
        const int co = co0 + t;
        float s = 0.f;
        for (int c = 0; c < NC; ++c) s += wv[(size_t)co * NC + c] * xsum[b * NC + c];
        vsum[b * NC + co] = s + (float)NN * bv[co];
    }
    float acc[4][4] = {{0.f}};
    for (int cc = 0; cc < NC; cc += 64) {
#pragma unroll 1
        for (int r = 0; r < 4; ++r) {
            const int idx = r * 256 + t;
            const int row = idx >> 4, a = (idx & 15) * 4;
            *(float4*)&m1s[row * 68 + a] = *(const float4*)&mat1[((size_t)b * NQ + row) * NC + cc + a];
            *(float4*)&wvs[row * 68 + a] = *(const float4*)&wv[(size_t)(co0 + row) * NC + cc + a];
        }
        __syncthreads();
#pragma unroll 8
        for (int c4 = 0; c4 < 16; ++c4) {
            float4 mr[4], wr[4];
#pragma unroll
            for (int jo = 0; jo < 4; ++jo) mr[jo] = *(const float4*)&m1s[(ty + 16 * jo) * 68 + c4 * 4];
#pragma unroll
            for (int jc = 0; jc < 4; ++jc) wr[jc] = *(const float4*)&wvs[(tx + 16 * jc) * 68 + c4 * 4];
#pragma unroll
            for (int jo = 0; jo < 4; ++jo)
#pragma unroll
                for (int jc = 0; jc < 4; ++jc)
                    acc[jo][jc] += mr[jo].x * wr[jc].x + mr[jo].y * wr[jc].y +
                                   mr[jo].z * wr[jc].z + mr[jo].w * wr[jc].w;
        }
        __syncthreads();
    }
#pragma unroll
    for (int jo = 0; jo < 4; ++jo) {
        const float ks = ksum[b * NQ + ty + 16 * jo];
#pragma unroll
        for (int jc = 0; jc < 4; ++jc) {
            const int co = co0 + tx + 16 * jc;
            mat2[((size_t)b * NQ + ty + 16 * jo) * NC + co] = acc[jo][jc] + ks * bv[co];
        }
    }
}

// -------- out = x + gamma * (vsum[c] + Qt^T mat2) * tailor --------
// grid (144, 8), block 256. Thread: a=t&15 -> 4 consecutive positions, cq=t>>4 -> 4 channels.
__launch_bounds__(256, 4)
__global__ void final_kernel(const float* __restrict__ x, const float* __restrict__ Qt,
                             const float* __restrict__ ksum, const float* __restrict__ mat2,
                             const float* __restrict__ vsum, const float* __restrict__ gamma,
                             float* __restrict__ out) {
    __shared__ __align__(16) float qs[64 * 64];   // [o][p] stride 64 (global_load_lds)
    __shared__ __align__(16) float m2s[64 * 68];  // [o][c]
    __shared__ float vs[64];
    __shared__ float ksl[64];
    __shared__ float tl[64];
    const int t = threadIdx.x;
    const int a = t & 15, cq = t >> 4;
    const int wid = t >> 6, lane = t & 63;
    const int lrow = lane >> 4, lcol = (lane & 15) * 4;
    const int b = blockIdx.y;
    const int n0 = blockIdx.x * 64;
#pragma unroll
    for (int q = 0; q < 4; ++q) {
        const int o0 = q * 16 + wid * 4;
        load_lds16(Qt + ((size_t)b * NQ + o0 + lrow) * NN + n0 + lcol, &qs[o0 * 64]);
    }
    if (t < 64) ksl[t] = ksum[b * NQ + t] + FEPS;
    __syncthreads();
    if (t < 64) {
        float s = 0.f;
#pragma unroll 8
        for (int o = 0; o < 64; ++o) s += qs[o * 64 + t] * ksl[o];
        tl[t] = 1.0f / ((float)NN + s);
    }
    __syncthreads();
    const float g = gamma[0];
    const float4 tlr = *(const float4*)&tl[a * 4];
    for (int cc = 0; cc < NC; cc += 64) {
#pragma unroll 1
        for (int r = 0; r < 4; ++r) {
            const int idx = r * 256 + t;
            const int o = idx >> 4, a4 = (idx & 15) * 4;
            *(float4*)&m2s[o * 68 + a4] = *(const float4*)&mat2[((size_t)b * NQ + o) * NC + cc + a4];
        }
        if (t < 64) vs[t] = vsum[b * NC + cc + t];
        __syncthreads();
        float acc[4][4];  // [u channel][e position]
#pragma unroll
        for (int u = 0; u < 4; ++u)
#pragma unroll
            for (int e = 0; e < 4; ++e) acc[u][e] = 0.f;
#pragma unroll 8
        for (int o = 0; o < 64; ++o) {
            const float4 qv = *(const float4*)&qs[o * 64 + a * 4];
            const float m0 = m2s[o * 68 + cq];
            const float m1 = m2s[o * 68 + cq + 16];
            const float m2v = m2s[o * 68 + cq + 32];
            const float m3 = m2s[o * 68 + cq + 48];
            acc[0][0] += qv.x * m0; acc[0][1] += qv.y * m0; acc[0][2] += qv.z * m0; acc[0][3] += qv.w * m0;
            acc[1][0] += qv.x * m1; acc[1][1] += qv.y * m1; acc[1][2] += qv.z * m1; acc[1][3] += qv.w * m1;
            acc[2][0] += qv.x * m2v; acc[2][1] += qv.y * m2v; acc[2][2] += qv.z * m2v; acc[2][3] += qv.w * m2v;
            acc[3][0] += qv.x * m3; acc[3][1] += qv.y * m3; acc[3][2] += qv.z * m3; acc[3][3] += qv.w * m3;
        }
#pragma unroll
        for (int u = 0; u < 4; ++u) {
            const int c = cc + cq + 16 * u;
            const size_t gi = ((size_t)b * NC + c) * NN + n0 + a * 4;
            const float4 xv = *(const float4*)&x[gi];
            const float vsv = vs[cq + 16 * u];
            float4 ov;
            ov.x = xv.x + g * (vsv + acc[u][0]) * tlr.x;
            ov.y = xv.y + g * (vsv + acc[u][1]) * tlr.y;
            ov.z = xv.z + g * (vsv + acc[u][2]) * tlr.z;
            ov.w = xv.w + g * (vsv + acc[u][3]) * tlr.w;
            *(float4*)&out[gi] = ov;
        }
        __syncthreads();
    }
}

extern "C" void kernel_launch(void* const* d_in, const int* in_sizes, int n_in,
                              void* d_out, int out_size, void* d_ws, size_t ws_size,
                              hipStream_t stream) {
    (void)in_sizes; (void)n_in; (void)out_size; (void)ws_size;
    const float* x     = (const float*)d_in[0];
    const float* wq    = (const float*)d_in[1];
    const float* bq    = (const float*)d_in[2];
    const float* wk    = (const float*)d_in[3];
    const float* bk    = (const float*)d_in[4];
    const float* wv    = (const float*)d_in[5];
    const float* bv    = (const float*)d_in[6];
    const float* gamma = (const float*)d_in[7];
    float* out = (float*)d_out;
    float* ws  = (float*)d_ws;

    float* Qt   = ws + OFF_Q;
    float* Kt   = ws + OFF_KT;
    float* ksum = ws + OFF_KSUM;
    float* xsum = ws + OFF_XSUM;
    float* m1   = ws + OFF_M1;
    float* m2   = ws + OFF_M2;
    float* vsum = ws + OFF_VSUM;

    // zero all atomically-accumulated buffers (ksum, xsum, mat1 are contiguous)
    hipMemsetAsync(ksum, 0, (size_t)(NB * NQ + NB * NC + NB * NQ * NC) * sizeof(float), stream);

    qk_proj_kernel<<<dim3(NN / 64, NB), 256, 0, stream>>>(x, wq, bq, wk, bk, Qt, Kt, ksum);
    kxt_kernel<<<dim3(8, 8, NB), 256, 0, stream>>>(x, Kt, m1, xsum);
    mat2_kernel<<<dim3(8, NB), 256, 0, stream>>>(wv, bv, m1, ksum, xsum, m2, vsum);
    final_kernel<<<dim3(NN / 64, NB), 256, 0, stream>>>(x, Qt, ksum, m2, vsum, gamma, out);
}